// Round 7
// baseline (377.803 us; speedup 1.0000x reference)
//
#include <hip/hip_runtime.h>
#include <math.h>

#define ROWS 2048
#define COLS 32768
#define TOPK 10

// sigmoid(x/T) = 1/(1+exp(-x/T)) = 1/(1+exp2(x * -log2(e)/T)), T=2.5
constexpr float EXP2_SCALE = -0.57707801635558534f;   // -log2(e)/2.5
constexpr float EPS_F      = 1e-10f;

__device__ __forceinline__ float sigmoid_t(float x) {
    return __builtin_amdgcn_rcpf(1.0f + exp2f(x * EXP2_SCALE));
}

// One block per row, 256 threads = 4 waves.
// Depth-2 software pipeline: the NEXT float4 load is issued before the
// branchy top-10 insertion of the CURRENT float4, so each wave always has a
// global load in flight (the exec-mask save/restore around the insertion
// ladder otherwise blocks the compiler from hoisting loads across it).
__global__ __launch_bounds__(256, 4) void row_topk_kernel(
        const float* __restrict__ S, float* __restrict__ accum) {
    const int row  = blockIdx.x;
    const int tid  = threadIdx.x;
    const int lane = tid & 63;
    const int wid  = tid >> 6;

    __shared__ float cand[4 * TOPK];
    __shared__ float wsum[4];

    const float4* rowp = (const float4*)(S + (size_t)row * COLS);

    float top[TOPK];                       // top[0]=max ... top[9]=min, static idx
#pragma unroll
    for (int i = 0; i < TOPK; ++i) top[i] = -INFINITY;

    float ssum = 0.0f;

    constexpr int ITERS = COLS / 4 / 256;  // 32
    float4 cur = rowp[tid];

#pragma unroll 4
    for (int i = 0; i < ITERS; ++i) {
        float4 nxt;
        if (i + 1 < ITERS) nxt = rowp[(i + 1) * 256 + tid];  // issue early

        // ---- process cur ----
        ssum += (sigmoid_t(cur.x) + sigmoid_t(cur.y)) +
                (sigmoid_t(cur.z) + sigmoid_t(cur.w));

        float m4 = fmaxf(fmaxf(cur.x, cur.y), fmaxf(cur.z, cur.w));
        if (m4 > top[TOPK - 1]) {          // one wave-predicated entry per float4
            float xs[4] = {cur.x, cur.y, cur.z, cur.w};
#pragma unroll
            for (int c = 0; c < 4; ++c) {
                float x = xs[c];
                if (x > top[TOPK - 1]) {
                    top[TOPK - 1] = x;
#pragma unroll
                    for (int j = TOPK - 1; j > 0; --j) {
                        float a = top[j - 1], b = top[j];
                        top[j - 1] = fmaxf(a, b);
                        top[j]     = fminf(a, b);
                    }
                }
            }
        }
        cur = nxt;
    }

    // ---- wave reduce the sigmoid sum ----
#pragma unroll
    for (int off = 32; off >= 1; off >>= 1)
        ssum += __shfl_xor(ssum, off, 64);
    if (lane == 0) wsum[wid] = ssum;

    // ---- wave-level top-10 extraction ----
#pragma unroll
    for (int k = 0; k < TOPK; ++k) {
        float m = top[0];
#pragma unroll
        for (int off = 32; off >= 1; off >>= 1)
            m = fmaxf(m, __shfl_xor(m, off, 64));
        unsigned long long b = __ballot(top[0] == m);
        int src = __ffsll(b) - 1;          // remove exactly one copy of the max
        if (lane == src) {
#pragma unroll
            for (int j = 0; j < TOPK - 1; ++j) top[j] = top[j + 1];
            top[TOPK - 1] = -INFINITY;
        }
        if (lane == 0) cand[wid * TOPK + k] = m;
    }
    __syncthreads();

    // ---- final merge: 40 candidates -> global top-10, wave 0 only ----
    if (wid == 0) {
        float v = (lane < 4 * TOPK) ? cand[lane] : -INFINITY;
        float num = 0.0f;
#pragma unroll
        for (int k = 0; k < TOPK; ++k) {
            float m = v;
#pragma unroll
            for (int off = 32; off >= 1; off >>= 1)
                m = fmaxf(m, __shfl_xor(m, off, 64));
            unsigned long long b = __ballot(v == m);
            int src = __ffsll(b) - 1;
            if (lane == src) v = -INFINITY;
            num += sigmoid_t(m);           // uniform across lanes
        }
        if (lane == 0) {
            float den = wsum[0] + wsum[1] + wsum[2] + wsum[3];
            float stk = num / den;
            atomicAdd(accum, stk * __logf(stk + EPS_F));
        }
    }
}

__global__ void finalize_kernel(const float* __restrict__ accum,
                                float* __restrict__ out) {
    out[0] = -accum[0] * (1.0f / (float)ROWS);
}

extern "C" void kernel_launch(void* const* d_in, const int* in_sizes, int n_in,
                              void* d_out, int out_size, void* d_ws, size_t ws_size,
                              hipStream_t stream) {
    const float* S   = (const float*)d_in[0];
    float* out       = (float*)d_out;
    float* accum     = (float*)d_ws;

    // d_ws is re-poisoned to 0xAA before every launch — zero the accumulator.
    hipMemsetAsync(accum, 0, sizeof(float), stream);

    row_topk_kernel<<<ROWS, 256, 0, stream>>>(S, accum);
    finalize_kernel<<<1, 1, 0, stream>>>(accum, out);
}